// Round 18
// baseline (97117.426 us; speedup 1.0000x reference)
//
#include <hip/hip_runtime.h>

#define FPS_T 1024           // preprocess block size
#define FPS_K 16
#define NW    (FPS_T / 64)
#define NCELL 512            // 8x8x8 spatial grid
#define CHK   4              // chunks per lane (fps: 64 lanes x 4 x 64 = 16384)
#define CPTS  64             // points per chunk

// FROZEN golden arithmetic (verified absmax=0 in R12..R17): f32, LLVM-DAG order
//   d = fma(dz,dz, fma(dx,dx, rn(dy*dy)))
__device__ __forceinline__ float sqd_f32dag(float ax, float ay, float az,
                                            float bx, float by, float bz) {
    const float dx = __fsub_rn(ax, bx);
    const float dy = __fsub_rn(ay, by);
    const float dz = __fsub_rn(az, bz);
    float acc = __fmul_rn(dy, dy);
    acc = __builtin_fmaf(dx, dx, acc);
    acc = __builtin_fmaf(dz, dz, acc);
    return acc;
}

// Counting-sort each cloud by 8x8x8 cell id into float4 {x,y,z, bits(16383-orig)}.
// (verified R15..R17)
__global__ __launch_bounds__(1024) void preprocess_kernel(const float* __restrict__ pos,
                                                          float4* __restrict__ pxyz,
                                                          int P) {
    const int b = blockIdx.x, t = threadIdx.x;
    const float* posb = pos + (size_t)b * P * 3;
    float4* PB = pxyz + (size_t)b * P;

    __shared__ unsigned hist[NCELL];
    __shared__ unsigned scanb[NCELL];
    __shared__ float s_red[NW][8];

    float x[FPS_K], y[FPS_K], z[FPS_K];
    float lx = 1e30f, ly = 1e30f, lz = 1e30f, hx = -1e30f, hy = -1e30f, hz = -1e30f;
#pragma unroll
    for (int k = 0; k < FPS_K; ++k) {
        const int p = k * FPS_T + t;
        x[k] = posb[p * 3 + 0]; y[k] = posb[p * 3 + 1]; z[k] = posb[p * 3 + 2];
        lx = fminf(lx, x[k]); hx = fmaxf(hx, x[k]);
        ly = fminf(ly, y[k]); hy = fmaxf(hy, y[k]);
        lz = fminf(lz, z[k]); hz = fmaxf(hz, z[k]);
    }
#pragma unroll
    for (int off = 32; off >= 1; off >>= 1) {
        lx = fminf(lx, __shfl_xor(lx, off, 64)); hx = fmaxf(hx, __shfl_xor(hx, off, 64));
        ly = fminf(ly, __shfl_xor(ly, off, 64)); hy = fmaxf(hy, __shfl_xor(hy, off, 64));
        lz = fminf(lz, __shfl_xor(lz, off, 64)); hz = fmaxf(hz, __shfl_xor(hz, off, 64));
    }
    if ((t & 63) == 0) {
        const int w = t >> 6;
        s_red[w][0] = lx; s_red[w][1] = ly; s_red[w][2] = lz;
        s_red[w][3] = hx; s_red[w][4] = hy; s_red[w][5] = hz;
    }
    if (t < NCELL) hist[t] = 0;
    __syncthreads();
    lx = s_red[0][0]; ly = s_red[0][1]; lz = s_red[0][2];
    hx = s_red[0][3]; hy = s_red[0][4]; hz = s_red[0][5];
#pragma unroll
    for (int w = 1; w < NW; ++w) {
        lx = fminf(lx, s_red[w][0]); ly = fminf(ly, s_red[w][1]); lz = fminf(lz, s_red[w][2]);
        hx = fmaxf(hx, s_red[w][3]); hy = fmaxf(hy, s_red[w][4]); hz = fmaxf(hz, s_red[w][5]);
    }
    const float ivx = 8.0f / fmaxf(hx - lx, 1e-20f);
    const float ivy = 8.0f / fmaxf(hy - ly, 1e-20f);
    const float ivz = 8.0f / fmaxf(hz - lz, 1e-20f);

    int cid[FPS_K];
#pragma unroll
    for (int k = 0; k < FPS_K; ++k) {
        int cx = (int)((x[k] - lx) * ivx); cx = cx < 0 ? 0 : (cx > 7 ? 7 : cx);
        int cy = (int)((y[k] - ly) * ivy); cy = cy < 0 ? 0 : (cy > 7 ? 7 : cy);
        int cz = (int)((z[k] - lz) * ivz); cz = cz < 0 ? 0 : (cz > 7 ? 7 : cz);
        cid[k] = (cx << 6) | (cy << 3) | cz;
        atomicAdd(&hist[cid[k]], 1u);
    }
    __syncthreads();
    if (t < NCELL) scanb[t] = hist[t];
    __syncthreads();
    for (int off = 1; off < NCELL; off <<= 1) {
        unsigned add = 0;
        if (t < NCELL && t >= off) add = scanb[t - off];
        __syncthreads();
        if (t < NCELL) scanb[t] += add;
        __syncthreads();
    }
    if (t < NCELL) hist[t] = scanb[t] - hist[t];
    __syncthreads();
#pragma unroll
    for (int k = 0; k < FPS_K; ++k) {
        const int p = k * FPS_T + t;
        const unsigned dst = atomicAdd(&hist[cid[k]], 1u);
        PB[dst] = make_float4(x[k], y[k], z[k], __uint_as_float((unsigned)(16383 - p)));
    }
}

// ONE WAVE per cloud: no barriers, no cross-wave reduce, md lane-private in LDS.
__global__ __launch_bounds__(64) void fps_kernel(const float* __restrict__ pos,
                                                 const float4* __restrict__ pxyz,
                                                 int* __restrict__ idx_out,
                                                 int P, int M) {
#pragma clang fp contract(off)
    const int b = blockIdx.x, lane = threadIdx.x;
    const float* posb = pos + (size_t)b * P * 3;
    const float4* PB = pxyz + (size_t)b * P;

    __shared__ float mdl[16384];      // 64 KB; lane-private ranges, never synced

    // Per-chunk state in registers: bbox, cached argmax (val, pay, coords).
    float blx[CHK], bly[CHK], blz[CHK], bhx[CHK], bhy[CHK], bhz[CHK];
    float cvalc[CHK]; unsigned cpayc[CHK];
    float cbxc[CHK], cbyc[CHK], cbzc[CHK];

    const int base0 = lane * (CHK * CPTS);
#pragma unroll
    for (int c = 0; c < CHK; ++c) {
        const int cb = base0 + c * CPTS;
        float lx = 1e30f, ly = 1e30f, lz = 1e30f, hx = -1e30f, hy = -1e30f, hz = -1e30f;
        for (int j = 0; j < CPTS; ++j) {
            const float4 v = PB[cb + j];
            lx = fminf(lx, v.x); hx = fmaxf(hx, v.x);
            ly = fminf(ly, v.y); hy = fmaxf(hy, v.y);
            lz = fminf(lz, v.z); hz = fmaxf(hz, v.z);
            mdl[cb + j] = __builtin_inff();
        }
        blx[c] = lx; bly[c] = ly; blz[c] = lz;
        bhx[c] = hx; bhy[c] = hy; bhz[c] = hz;
        cvalc[c] = __builtin_inff(); cpayc[c] = 0u;
        cbxc[c] = 0.f; cbyc[c] = 0.f; cbzc[c] = 0.f;
    }
    if (lane == 0) idx_out[(size_t)b * M] = 0;

    float sx = posb[0], sy = posb[1], sz = posb[2];

    for (int m = 1; m < M; ++m) {
        // ---- per-chunk exact bbox skip (R15-proven: recompute iff bb < max_md*(1+2^-14)) ----
#pragma unroll
        for (int c = 0; c < CHK; ++c) {
            const float qx = fminf(fmaxf(sx, blx[c]), bhx[c]);
            const float qy = fminf(fmaxf(sy, bly[c]), bhy[c]);
            const float qz = fminf(fmaxf(sz, blz[c]), bhz[c]);
            const float bb = sqd_f32dag(qx, qy, qz, sx, sy, sz);
            const bool act = bb < cvalc[c] * 1.00006104f;   // *(1+2^-14)
            if (__ballot(act) != 0ull) {
                if (act) {
                    const int cb = base0 + c * CPTS;
                    float bv = -1.0f; unsigned bp = 0u;
                    float bx = 0.f, by = 0.f, bz = 0.f;
                    for (int j = 0; j < CPTS; j += 4) {
                        const float4 q0 = PB[cb + j + 0];
                        const float4 q1 = PB[cb + j + 1];
                        const float4 q2 = PB[cb + j + 2];
                        const float4 q3 = PB[cb + j + 3];
                        float4 m4 = *reinterpret_cast<const float4*>(&mdl[cb + j]);
                        const float d0 = sqd_f32dag(q0.x, q0.y, q0.z, sx, sy, sz);
                        const float d1 = sqd_f32dag(q1.x, q1.y, q1.z, sx, sy, sz);
                        const float d2 = sqd_f32dag(q2.x, q2.y, q2.z, sx, sy, sz);
                        const float d3 = sqd_f32dag(q3.x, q3.y, q3.z, sx, sy, sz);
                        m4.x = fminf(m4.x, d0); m4.y = fminf(m4.y, d1);
                        m4.z = fminf(m4.z, d2); m4.w = fminf(m4.w, d3);
                        *reinterpret_cast<float4*>(&mdl[cb + j]) = m4;
                        // exact (val, tor) order; pay = (tor<<14)|spos, tor unique
                        const unsigned p0 = (__float_as_uint(q0.w) << 14) | (unsigned)(cb + j + 0);
                        const unsigned p1 = (__float_as_uint(q1.w) << 14) | (unsigned)(cb + j + 1);
                        const unsigned p2 = (__float_as_uint(q2.w) << 14) | (unsigned)(cb + j + 2);
                        const unsigned p3 = (__float_as_uint(q3.w) << 14) | (unsigned)(cb + j + 3);
                        if (m4.x > bv || (m4.x == bv && p0 > bp)) { bv = m4.x; bp = p0; bx = q0.x; by = q0.y; bz = q0.z; }
                        if (m4.y > bv || (m4.y == bv && p1 > bp)) { bv = m4.y; bp = p1; bx = q1.x; by = q1.y; bz = q1.z; }
                        if (m4.z > bv || (m4.z == bv && p2 > bp)) { bv = m4.z; bp = p2; bx = q2.x; by = q2.y; bz = q2.z; }
                        if (m4.w > bv || (m4.w == bv && p3 > bp)) { bv = m4.w; bp = p3; bx = q3.x; by = q3.y; bz = q3.z; }
                    }
                    cvalc[c] = bv; cpayc[c] = bp;
                    cbxc[c] = bx; cbyc[c] = by; cbzc[c] = bz;
                }
            }
        }
        // ---- lane merged best over 4 chunk caches (exact (val,pay) order) ----
        float v = cvalc[0]; unsigned p = cpayc[0];
        float mx = cbxc[0], my = cbyc[0], mz = cbzc[0];
#pragma unroll
        for (int c = 1; c < CHK; ++c) {
            const bool bet = (cvalc[c] > v) || (cvalc[c] == v && cpayc[c] > p);
            if (bet) { v = cvalc[c]; p = cpayc[c]; mx = cbxc[c]; my = cbyc[c]; mz = cbzc[c]; }
        }
        // ---- 64-lane u64 butterfly (val monotone bits; pay tiebreak = first-occurrence) ----
        unsigned long long key = ((unsigned long long)__float_as_uint(v) << 32) | p;
#pragma unroll
        for (int off = 32; off >= 1; off >>= 1) {
            const unsigned long long o = __shfl_xor(key, off, 64);
            if (o > key) key = o;
        }
        const unsigned gp = (unsigned)key;
        if (lane == 0) idx_out[(size_t)b * M + m] = 16383 - (int)((gp >> 14) & 0x3FFFu);
        // ---- winner coords via in-wave shuffle from owning lane (spos>>8) ----
        const int wl = (int)((gp & 0x3FFFu) >> 8);
        sx = __shfl(mx, wl, 64);
        sy = __shfl(my, wl, 64);
        sz = __shfl(mz, wl, 64);
    }
}

// Gather: out = [x[gidx] (BM x 128 f32)] ++ [pos[gidx] (BM x 3 f32)] ++ [batch[gidx] (BM f32)]
__global__ __launch_bounds__(256) void gather_kernel(const float* __restrict__ x,
                                                     const float* __restrict__ pos,
                                                     const int* __restrict__ idx,
                                                     float* __restrict__ out,
                                                     int P, int M, int F, int BM) {
    const int r    = blockIdx.x * 8 + (threadIdx.x >> 5);
    const int lane = threadIdx.x & 31;
    if (r >= BM) return;
    const int b  = r / M;
    const int li = idx[r];
    const size_t g = (size_t)b * P + li;

    const float4* xr   = reinterpret_cast<const float4*>(x + g * (size_t)F);
    float4*       orow = reinterpret_cast<float4*>(out + (size_t)r * F);
    orow[lane] = xr[lane];

    const size_t pos_base   = (size_t)BM * F;
    const size_t batch_base = pos_base + (size_t)BM * 3;
    if (lane < 3)  out[pos_base + (size_t)r * 3 + lane] = pos[g * 3 + lane];
    if (lane == 3) out[batch_base + r] = (float)b;
}

extern "C" void kernel_launch(void* const* d_in, const int* in_sizes, int n_in,
                              void* d_out, int out_size, void* d_ws, size_t ws_size,
                              hipStream_t stream) {
    const float* x   = (const float*)d_in[0];
    const float* pos = (const float*)d_in[1];
    const int N = in_sizes[2];          // 262144
    const int F = in_sizes[0] / N;      // 128
    const int B = 16;
    const int P = N / B;                // 16384
    const int M = P / 4;                // 4096
    const int BM = B * M;               // 65536
    const int PP = B * P;               // 262144

    int* idx_ws = (int*)d_ws;           // BM ints = 256 KB

    // Sorted-cloud scratch (float4/point = 4 MB) in the TAIL of d_out: consumed
    // by fps_kernel strictly before gather_kernel overwrites out.
    float* out_f = (float*)d_out;
    float4* pxyz = (float4*)(out_f + (out_size - 4 * PP));

    preprocess_kernel<<<B, FPS_T, 0, stream>>>(pos, pxyz, P);
    fps_kernel<<<B, 64, 0, stream>>>(pos, pxyz, idx_ws, P, M);
    gather_kernel<<<(BM + 7) / 8, 256, 0, stream>>>(x, pos, idx_ws, (float*)d_out, P, M, F, BM);
}

// Round 19
// 8205.173 us; speedup vs baseline: 11.8361x; 11.8361x over previous
//
#include <hip/hip_runtime.h>

#define FPS_T 1024
#define FPS_K 16
#define NW    (FPS_T / 64)   // 16 waves
#define NCELL 512            // 8x8x8 spatial grid

// FROZEN golden arithmetic (verified absmax=0 in R12..R18): f32, LLVM-DAG order
//   d = fma(dz,dz, fma(dx,dx, rn(dy*dy)))
__device__ __forceinline__ float sqd_f32dag(float ax, float ay, float az,
                                            float bx, float by, float bz) {
    const float dx = __fsub_rn(ax, bx);
    const float dy = __fsub_rn(ay, by);
    const float dz = __fsub_rn(az, bz);
    float acc = __fmul_rn(dy, dy);
    acc = __builtin_fmaf(dx, dx, acc);
    acc = __builtin_fmaf(dz, dz, acc);
    return acc;
}

// Counting-sort each cloud by 8x8x8 cell id into float4 {x,y,z, bits(16383-orig)}.
// (verified R15..R18)
__global__ __launch_bounds__(1024) void preprocess_kernel(const float* __restrict__ pos,
                                                          float4* __restrict__ pxyz,
                                                          int P) {
    const int b = blockIdx.x, t = threadIdx.x;
    const float* posb = pos + (size_t)b * P * 3;
    float4* PB = pxyz + (size_t)b * P;

    __shared__ unsigned hist[NCELL];
    __shared__ unsigned scanb[NCELL];
    __shared__ float s_red[NW][8];

    float x[FPS_K], y[FPS_K], z[FPS_K];
    float lx = 1e30f, ly = 1e30f, lz = 1e30f, hx = -1e30f, hy = -1e30f, hz = -1e30f;
#pragma unroll
    for (int k = 0; k < FPS_K; ++k) {
        const int p = k * FPS_T + t;
        x[k] = posb[p * 3 + 0]; y[k] = posb[p * 3 + 1]; z[k] = posb[p * 3 + 2];
        lx = fminf(lx, x[k]); hx = fmaxf(hx, x[k]);
        ly = fminf(ly, y[k]); hy = fmaxf(hy, y[k]);
        lz = fminf(lz, z[k]); hz = fmaxf(hz, z[k]);
    }
#pragma unroll
    for (int off = 32; off >= 1; off >>= 1) {
        lx = fminf(lx, __shfl_xor(lx, off, 64)); hx = fmaxf(hx, __shfl_xor(hx, off, 64));
        ly = fminf(ly, __shfl_xor(ly, off, 64)); hy = fmaxf(hy, __shfl_xor(hy, off, 64));
        lz = fminf(lz, __shfl_xor(lz, off, 64)); hz = fmaxf(hz, __shfl_xor(hz, off, 64));
    }
    if ((t & 63) == 0) {
        const int w = t >> 6;
        s_red[w][0] = lx; s_red[w][1] = ly; s_red[w][2] = lz;
        s_red[w][3] = hx; s_red[w][4] = hy; s_red[w][5] = hz;
    }
    if (t < NCELL) hist[t] = 0;
    __syncthreads();
    lx = s_red[0][0]; ly = s_red[0][1]; lz = s_red[0][2];
    hx = s_red[0][3]; hy = s_red[0][4]; hz = s_red[0][5];
#pragma unroll
    for (int w = 1; w < NW; ++w) {
        lx = fminf(lx, s_red[w][0]); ly = fminf(ly, s_red[w][1]); lz = fminf(lz, s_red[w][2]);
        hx = fmaxf(hx, s_red[w][3]); hy = fmaxf(hy, s_red[w][4]); hz = fmaxf(hz, s_red[w][5]);
    }
    const float ivx = 8.0f / fmaxf(hx - lx, 1e-20f);
    const float ivy = 8.0f / fmaxf(hy - ly, 1e-20f);
    const float ivz = 8.0f / fmaxf(hz - lz, 1e-20f);

    int cid[FPS_K];
#pragma unroll
    for (int k = 0; k < FPS_K; ++k) {
        int cx = (int)((x[k] - lx) * ivx); cx = cx < 0 ? 0 : (cx > 7 ? 7 : cx);
        int cy = (int)((y[k] - ly) * ivy); cy = cy < 0 ? 0 : (cy > 7 ? 7 : cy);
        int cz = (int)((z[k] - lz) * ivz); cz = cz < 0 ? 0 : (cz > 7 ? 7 : cz);
        cid[k] = (cx << 6) | (cy << 3) | cz;
        atomicAdd(&hist[cid[k]], 1u);
    }
    __syncthreads();
    if (t < NCELL) scanb[t] = hist[t];
    __syncthreads();
    for (int off = 1; off < NCELL; off <<= 1) {
        unsigned add = 0;
        if (t < NCELL && t >= off) add = scanb[t - off];
        __syncthreads();
        if (t < NCELL) scanb[t] += add;
        __syncthreads();
    }
    if (t < NCELL) hist[t] = scanb[t] - hist[t];
    __syncthreads();
#pragma unroll
    for (int k = 0; k < FPS_K; ++k) {
        const int p = k * FPS_T + t;
        const unsigned dst = atomicAdd(&hist[cid[k]], 1u);
        PB[dst] = make_float4(x[k], y[k], z[k], __uint_as_float((unsigned)(16383 - p)));
    }
}

__global__ __launch_bounds__(1024) void fps_kernel(const float* __restrict__ pos,
                                                   const float4* __restrict__ pxyz,
                                                   int* __restrict__ idx_out,
                                                   int P, int M) {
#pragma clang fp contract(off)
    const int b = blockIdx.x, t = threadIdx.x;
    const int lane = t & 63, w = t >> 6;
    const float* posb = pos + (size_t)b * P * 3;
    const float4* PB = pxyz + (size_t)b * P;

    // Double-buffered per-wave winner slots: key + winner coords (owner-written).
    __shared__ unsigned long long s_key[2][NW];
    __shared__ float s_wx[2][NW], s_wy[2][NW], s_wz[2][NW];

    // Thread owns 16 consecutive sorted points: coords/md/payload in registers.
    float px[FPS_K], py[FPS_K], pz[FPS_K], md[FPS_K];
    unsigned pay[FPS_K];                 // (tor<<14) | sorted_pos  (28 bits, unique)
    const int sp0 = t * FPS_K;
#pragma unroll
    for (int k = 0; k < FPS_K; ++k) {
        const float4 v = PB[sp0 + k];
        px[k] = v.x; py[k] = v.y; pz[k] = v.z;
        pay[k] = (__float_as_uint(v.w) << 14) | (unsigned)(sp0 + k);
        md[k] = __builtin_inff();        // fminf(+inf, d) == d bitwise
    }
    float blx = px[0], bhx = px[0], bly = py[0], bhy = py[0], blz = pz[0], bhz = pz[0];
#pragma unroll
    for (int k = 1; k < FPS_K; ++k) {
        blx = fminf(blx, px[k]); bhx = fmaxf(bhx, px[k]);
        bly = fminf(bly, py[k]); bhy = fmaxf(bhy, py[k]);
        blz = fminf(blz, pz[k]); bhz = fmaxf(bhz, pz[k]);
    }
    if (t == 0) idx_out[(size_t)b * M] = 0;

    float sx = posb[0], sy = posb[1], sz = posb[2];
    // Cached per-thread best key + coords (valid while skip proves md unchanged).
    unsigned long long ckey = 0ull, wkey = 0ull;
    float cbx = 0.f, cby = 0.f, cbz = 0.f;
    float thresh = __builtin_inff();

    for (int m = 1; m < M; ++m) {
        const int buf = m & 1;
        // ---- exact bbox skip (R15-proven): recompute iff bb < local_max*(1+2^-14) ----
        const float cx = fminf(fmaxf(sx, blx), bhx);
        const float cy = fminf(fmaxf(sy, bly), bhy);
        const float cz = fminf(fmaxf(sz, blz), bhz);
        const float bb = sqd_f32dag(cx, cy, cz, sx, sy, sz);
        const bool active = bb < thresh;
        if (__ballot(active) != 0ull) {
            if (active) {
                float bv = -1.0f; unsigned bp = 0u;
                float bx = 0.f, by = 0.f, bz = 0.f;
#pragma unroll
                for (int k = 0; k < FPS_K; ++k) {
                    const float d  = sqd_f32dag(px[k], py[k], pz[k], sx, sy, sz);
                    const float nm = fminf(md[k], d);
                    md[k] = nm;
                    // exact (val, tor) lexicographic order (== R15's u64 key compare)
                    const bool better = (nm > bv) || (nm == bv && pay[k] > bp);
                    if (better) { bv = nm; bp = pay[k]; bx = px[k]; by = py[k]; bz = pz[k]; }
                }
                ckey = ((unsigned long long)__float_as_uint(bv) << 32) | bp;
                cbx = bx; cby = by; cbz = bz;
                thresh = bv * 1.00006104f;   // *(1+2^-14)
            }
            unsigned long long key = ckey;
#pragma unroll
            for (int off = 32; off >= 1; off >>= 1) {
                const unsigned long long o = __shfl_xor(key, off, 64);
                if (o > key) key = o;
            }
            wkey = key;   // cached while wave fully skips (md only decreases)
        }
        // Unique owner lane (ckey==wkey) deposits key + coords every iteration.
        if (ckey == wkey) {
            s_key[buf][w] = wkey;
            s_wx[buf][w] = cbx; s_wy[buf][w] = cby; s_wz[buf][w] = cbz;
        }
        __syncthreads();
        // ---- width-16 cross-wave tree over the 16 wave winners ----
        unsigned long long g = s_key[buf][lane & (NW - 1)];
#pragma unroll
        for (int off = NW / 2; off >= 1; off >>= 1) {
            const unsigned long long o = __shfl_xor(g, off, NW);
            if (o > g) g = o;
        }
        const unsigned gp = (unsigned)g;
        // rotate the global-store across waves (vmcnt drain never hits one wave twice)
        if (t == ((m & 15) << 6)) idx_out[(size_t)b * M + m] = 16383 - (int)((gp >> 14) & 0x3FFFu);
        // ---- winner coords: broadcast LDS read from the winning wave's slot ----
        const int ww = (int)((gp & 0x3FFFu) >> 10);
        sx = s_wx[buf][ww]; sy = s_wy[buf][ww]; sz = s_wz[buf][ww];
    }
}

// Gather: out = [x[gidx] (BM x 128 f32)] ++ [pos[gidx] (BM x 3 f32)] ++ [batch[gidx] (BM f32)]
__global__ __launch_bounds__(256) void gather_kernel(const float* __restrict__ x,
                                                     const float* __restrict__ pos,
                                                     const int* __restrict__ idx,
                                                     float* __restrict__ out,
                                                     int P, int M, int F, int BM) {
    const int r    = blockIdx.x * 8 + (threadIdx.x >> 5);
    const int lane = threadIdx.x & 31;
    if (r >= BM) return;
    const int b  = r / M;
    const int li = idx[r];
    const size_t g = (size_t)b * P + li;

    const float4* xr   = reinterpret_cast<const float4*>(x + g * (size_t)F);
    float4*       orow = reinterpret_cast<float4*>(out + (size_t)r * F);
    orow[lane] = xr[lane];

    const size_t pos_base   = (size_t)BM * F;
    const size_t batch_base = pos_base + (size_t)BM * 3;
    if (lane < 3)  out[pos_base + (size_t)r * 3 + lane] = pos[g * 3 + lane];
    if (lane == 3) out[batch_base + r] = (float)b;
}

extern "C" void kernel_launch(void* const* d_in, const int* in_sizes, int n_in,
                              void* d_out, int out_size, void* d_ws, size_t ws_size,
                              hipStream_t stream) {
    const float* x   = (const float*)d_in[0];
    const float* pos = (const float*)d_in[1];
    const int N = in_sizes[2];          // 262144
    const int F = in_sizes[0] / N;      // 128
    const int B = 16;
    const int P = N / B;                // 16384
    const int M = P / 4;                // 4096
    const int BM = B * M;               // 65536
    const int PP = B * P;               // 262144

    int* idx_ws = (int*)d_ws;           // BM ints = 256 KB

    // Sorted-cloud scratch (float4/point = 4 MB) in the TAIL of d_out: consumed
    // by fps_kernel strictly before gather_kernel overwrites out.
    float* out_f = (float*)d_out;
    float4* pxyz = (float4*)(out_f + (out_size - 4 * PP));

    preprocess_kernel<<<B, FPS_T, 0, stream>>>(pos, pxyz, P);
    fps_kernel<<<B, FPS_T, 0, stream>>>(pos, pxyz, idx_ws, P, M);
    gather_kernel<<<(BM + 7) / 8, 256, 0, stream>>>(x, pos, idx_ws, (float*)d_out, P, M, F, BM);
}